// Round 1
// baseline (651.431 us; speedup 1.0000x reference)
//
#include <hip/hip_runtime.h>
#include <hip/hip_bf16.h>
#include <cstdint>
#include <cstddef>

// LoRALinear: out[T,M] = x[T,N] @ (W + alpha*A@B^T)^T + b
// T=8192, M=4096, N=4096, RANK=8, alpha = 8.0/8 = 1.0
//
// Strategy: fold the rank-8 update into W_eff (f16, in ws), convert x to f16
// (in ws), then one bf16-class MFMA GEMM (m97-style 128x128 tile,
// global_load_lds width=16 staging, 16x16x32 f16 MFMA, 4 waves x 4x4 frags).

#define T_DIM 8192
#define M_DIM 4096
#define N_DIM 4096
#define RANK  8
#define ALPHA 1.0f

typedef _Float16 f16x8 __attribute__((ext_vector_type(8)));
typedef float    f32x4 __attribute__((ext_vector_type(4)));

// ---------------------------------------------------------------- prep 1
// W_eff[m][n] = f16( W[m][n] + alpha * sum_r A[m][r]*B[n][r] )
// one thread per 8 consecutive n. W read 64MB, Weff write 32MB -> ~15us.
__global__ void build_weff(const float* __restrict__ W,
                           const float* __restrict__ A,
                           const float* __restrict__ B,
                           _Float16* __restrict__ Weff) {
    int idx = blockIdx.x * blockDim.x + threadIdx.x;   // M*N/8 threads
    int m = idx >> 9;                                  // N/8 = 512 per row
    int n = (idx & 511) << 3;
    float a[RANK];
    const float* Am = A + m * RANK;
#pragma unroll
    for (int r = 0; r < RANK; ++r) a[r] = Am[r];
    const float* Wrow = W + (size_t)m * N_DIM + n;
    f16x8 o;
#pragma unroll
    for (int j = 0; j < 8; ++j) {
        const float* Bn = B + (size_t)(n + j) * RANK;  // 32B, L2-resident (128KB total)
        float acc = 0.f;
#pragma unroll
        for (int r = 0; r < RANK; ++r) acc += a[r] * Bn[r];
        o[j] = (_Float16)(Wrow[j] + ALPHA * acc);
    }
    *(f16x8*)(Weff + (size_t)m * N_DIM + n) = o;
}

// ---------------------------------------------------------------- prep 2
// x fp32 -> f16. read 128MB, write 64MB -> ~30us.
__global__ void cvt_x(const float* __restrict__ x, _Float16* __restrict__ xh) {
    size_t i = ((size_t)blockIdx.x * blockDim.x + threadIdx.x) * 8;
    f32x4 v0 = *(const f32x4*)(x + i);
    f32x4 v1 = *(const f32x4*)(x + i + 4);
    f16x8 o;
    o[0] = (_Float16)v0[0]; o[1] = (_Float16)v0[1];
    o[2] = (_Float16)v0[2]; o[3] = (_Float16)v0[3];
    o[4] = (_Float16)v1[0]; o[5] = (_Float16)v1[1];
    o[6] = (_Float16)v1[2]; o[7] = (_Float16)v1[3];
    *(f16x8*)(xh + i) = o;
}

// ---------------------------------------------------------------- GEMM
// C[t][m] = sum_k X[t][k] * Weff[m][k]  (both row-major, K inner => "B^T" GEMM)
// 128x128 block tile, BK=32 (one MFMA K-step), 256 thr = 4 waves in 2x2,
// each wave owns a 64x64 subtile = 4x4 frags of 16x16.

__device__ static inline void gld_lds16(const void* g, void* l) {
    __builtin_amdgcn_global_load_lds(
        (const __attribute__((address_space(1))) unsigned int*)g,
        (__attribute__((address_space(3))) unsigned int*)l, 16, 0, 0);
}

__global__ __launch_bounds__(256, 2)
void gemm_f16(const _Float16* __restrict__ X, const _Float16* __restrict__ Wt,
              const float* __restrict__ bias, float* __restrict__ out) {
    // Tiles are contiguous row-major [128][32] f16 — NO padding: global_load_lds
    // deposits at wave-uniform base + lane*16, layout must match exactly.
    __shared__ __align__(16) _Float16 lA[128 * 32];  // 8 KB
    __shared__ __align__(16) _Float16 lB[128 * 32];  // 8 KB

    const int tid  = threadIdx.x;
    const int lane = tid & 63;
    const int wave = tid >> 6;
    const int wr = wave >> 1, wc = wave & 1;   // 2x2 wave grid
    const int bx = blockIdx.x, by = blockIdx.y;

    const size_t rowX0 = (size_t)by * 128;     // T rows
    const size_t rowW0 = (size_t)bx * 128;     // M rows (= out cols)

    // staging map: thread t loads 8 f16 (16B): row = t/4 (+64 in round 1),
    // col8 = (t%4)*8.  LDS elem offset = t*8 (+2048) = base + lane*16 bytes. OK.
    const int srow = tid >> 2;
    const int scol = (tid & 3) << 3;

    // MFMA fragment coords: A/B operand: outer = lane&15, k = (lane>>4)*8 + j
    const int fr = lane & 15;
    const int fk = (lane >> 4) << 3;

    f32x4 acc[4][4] = {};

    for (int k0 = 0; k0 < N_DIM; k0 += 32) {
        gld_lds16(X  + (rowX0      + srow) * N_DIM + k0 + scol, &lA[tid * 8]);
        gld_lds16(X  + (rowX0 + 64 + srow) * N_DIM + k0 + scol, &lA[2048 + tid * 8]);
        gld_lds16(Wt + (rowW0      + srow) * N_DIM + k0 + scol, &lB[tid * 8]);
        gld_lds16(Wt + (rowW0 + 64 + srow) * N_DIM + k0 + scol, &lB[2048 + tid * 8]);
        asm volatile("s_waitcnt vmcnt(0)" ::: "memory");
        __syncthreads();

        f16x8 af[4], bf[4];
#pragma unroll
        for (int i = 0; i < 4; ++i)
            af[i] = *(const f16x8*)&lA[(wr * 64 + i * 16 + fr) * 32 + fk];
#pragma unroll
        for (int i = 0; i < 4; ++i)
            bf[i] = *(const f16x8*)&lB[(wc * 64 + i * 16 + fr) * 32 + fk];
#pragma unroll
        for (int i = 0; i < 4; ++i)
#pragma unroll
            for (int j = 0; j < 4; ++j)
                acc[i][j] = __builtin_amdgcn_mfma_f32_16x16x32_f16(
                    af[i], bf[j], acc[i][j], 0, 0, 0);
        __syncthreads();   // before next round overwrites the tiles
    }

    // epilogue: C/D layout col = lane&15 (B side = out col), row = (lane>>4)*4+reg
    const int crow0 = by * 128 + wr * 64;
    const int ccol0 = bx * 128 + wc * 64;
#pragma unroll
    for (int j = 0; j < 4; ++j) {
        const int col = ccol0 + j * 16 + (lane & 15);
        const float bv = bias[col];
#pragma unroll
        for (int i = 0; i < 4; ++i) {
            const int row = crow0 + i * 16 + ((lane >> 4) << 2);
#pragma unroll
            for (int r = 0; r < 4; ++r)
                out[(size_t)(row + r) * M_DIM + col] = acc[i][j][r] + bv;
        }
    }
}

// ---------------------------------------------------------------- launch
extern "C" void kernel_launch(void* const* d_in, const int* in_sizes, int n_in,
                              void* d_out, int out_size, void* d_ws, size_t ws_size,
                              hipStream_t stream) {
    const float* x = (const float*)d_in[0];
    const float* W = (const float*)d_in[1];
    const float* b = (const float*)d_in[2];
    const float* A = (const float*)d_in[3];
    const float* B = (const float*)d_in[4];
    float* out = (float*)d_out;

    // ws layout: [Weff f16: 32MB][Xh f16: 64MB]  (needs 96MB of ws)
    _Float16* Weff = (_Float16*)d_ws;
    _Float16* Xh   = (_Float16*)((char*)d_ws + (size_t)M_DIM * N_DIM * sizeof(_Float16));

    build_weff<<<(M_DIM / 8) * N_DIM / 256, 256, 0, stream>>>(W, A, B, Weff);
    cvt_x<<<((size_t)T_DIM * N_DIM / 8) / 256, 256, 0, stream>>>(x, Xh);

    dim3 grid(M_DIM / 128, T_DIM / 128);
    gemm_f16<<<grid, dim3(256, 1, 1), 0, stream>>>(Xh, Weff, b, out);
}